// Round 3
// baseline (463.847 us; speedup 1.0000x reference)
//
#include <hip/hip_runtime.h>

// Advect: minmod-limited flux stencil along last axis.
// L = 8192 (ghost-padded), OUT = L-4 = 8188 per row, rows = B*M = 4096.
// R3: 16 outputs/thread (4x float4 stores), 5x float4 loads per input
// (halo redundancy 1.25x vs 2.0x in R1), nontemporal stores (via native
// ext_vector_type — HIP float4 class is rejected by the builtin).

#define TH 2.0f

typedef float floatx4 __attribute__((ext_vector_type(4)));

__device__ __forceinline__ float minmod3(float a, float b, float c) {
    float mn = fminf(fminf(a, b), c);
    float mx = fmaxf(fmaxf(a, b), c);
    return (mn < 0.0f) ? fminf(mx, 0.0f) : mn;
}

__global__ __launch_bounds__(256) void advect_kernel(
    const float* __restrict__ rho, const float* __restrict__ v,
    float* __restrict__ out)
{
    const int L = 8192, OUT = 8188;
    int t = blockIdx.x * blockDim.x + threadIdx.x;   // 0..511 (covers 16 outputs each)
    long row = blockIdx.y;
    const float* r  = rho + row * (long)L;
    const float* vp = v   + row * (long)L;
    int k0 = t * 16;

    float R[20], V[20];
#pragma unroll
    for (int s = 0; s < 4; ++s) {
        floatx4 a = *(const floatx4*)(r + k0 + 4 * s);
        R[4*s+0] = a.x; R[4*s+1] = a.y; R[4*s+2] = a.z; R[4*s+3] = a.w;
        floatx4 b = *(const floatx4*)(vp + k0 + 4 * s);
        V[4*s+0] = b.x; V[4*s+1] = b.y; V[4*s+2] = b.z; V[4*s+3] = b.w;
    }
    if (k0 + 16 < L) {   // only the last thread per row (k0==8176) skips
        floatx4 a = *(const floatx4*)(r + k0 + 16);
        R[16] = a.x; R[17] = a.y; R[18] = a.z; R[19] = a.w;
        floatx4 b = *(const floatx4*)(vp + k0 + 16);
        V[16] = b.x; V[17] = b.y; V[18] = b.z; V[19] = b.w;
    } else {
        R[16] = R[17] = R[18] = R[19] = 0.0f;
        V[16] = V[17] = V[18] = V[19] = 0.0f;
    }

    float F[20];
#pragma unroll
    for (int i = 0; i < 20; ++i) F[i] = R[i] * V[i];

    // half-slope hs[i] ~ global index k0+i
    float hs[18];
#pragma unroll
    for (int i = 0; i < 18; ++i) {
        float c0 = TH   * (F[i+1] - F[i]);
        float c1 = 0.5f * (F[i+2] - F[i]);
        float c2 = TH   * (F[i+2] - F[i+1]);
        hs[i] = 0.5f * minmod3(c0, c1, c2);
    }

    // net[j] ~ global index k0+j
    float net[17];
#pragma unroll
    for (int j = 0; j < 17; ++j) {
        int gj = k0 + j;
        float fm = (V[j+2] >= 0.0f || gj == OUT) ? 0.0f : (F[j+2] - hs[j+1]);
        float fp = (V[j+1] <= 0.0f || gj == 0)   ? 0.0f : (F[j+1] + hs[j]);
        net[j] = fm + fp;
    }

    float* op = out + row * (long)OUT + k0;
#pragma unroll
    for (int s = 0; s < 4; ++s) {
        if (k0 + 4 * s + 3 < OUT) {   // last thread per row skips s==3
            floatx4 o;
            o.x = net[4*s+0] - net[4*s+1];
            o.y = net[4*s+1] - net[4*s+2];
            o.z = net[4*s+2] - net[4*s+3];
            o.w = net[4*s+3] - net[4*s+4];
            __builtin_nontemporal_store(o, (floatx4*)(op + 4 * s));
        }
    }
}

extern "C" void kernel_launch(void* const* d_in, const int* in_sizes, int n_in,
                              void* d_out, int out_size, void* d_ws, size_t ws_size,
                              hipStream_t stream) {
    const float* rho = (const float*)d_in[0];
    const float* v   = (const float*)d_in[1];
    float* out = (float*)d_out;

    const int L    = 8192;
    const int rows = in_sizes[0] / L;   // B*M = 4096
    // 512 threads per row, 16 outputs each (8192 >= 8188)
    dim3 block(256);
    dim3 grid(2, rows);
    hipLaunchKernelGGL(advect_kernel, grid, block, 0, stream, rho, v, out);
}